// Round 9
// baseline (2852.593 us; speedup 1.0000x reference)
//
#include <hip/hip_runtime.h>
#include <math.h>

#define N_NODES 100000
#define N_EDGES 1600000
#define D 128
#define N_LAYERS 3
#define N_GRAPHS 128
#define N_TARGETS 10
#define NEG_SLOPE 0.2f
#define E_TOT (N_EDGES + N_NODES)
#define CSR_W 64        /* fixed-width CSR rows; deg>64 handled by fallback scan */
#define N_BINS 8
#define BIN_NODES 12500 /* N_NODES / N_BINS */
#define BIN_CAP 400000  /* mean 212.5K, +400 sigma headroom; overflow falls back */

typedef unsigned int u32;
typedef unsigned short u16;
typedef unsigned long long u64;
typedef __attribute__((ext_vector_type(8))) short bf16x8;
typedef __attribute__((ext_vector_type(4))) float f32x4;

__device__ __forceinline__ float bf2f(u16 b) {
    u32 u = ((u32)b) << 16;
    return __uint_as_float(u);
}
__device__ __forceinline__ u16 f2bf(float f) {  // round-to-nearest-even
    u32 u = __float_as_uint(f);
    u32 r = (u + 0x7fffu + ((u >> 16) & 1u)) >> 16;
    return (u16)r;
}

// ---------------- CSR build phase A: bin edges by dst range ----------------
// Wave-aggregated cursor atomics; sequential appends at 8 hot bin tails.
__global__ __launch_bounds__(256) void binA_kernel(
        const int* __restrict__ src, const int* __restrict__ dst,
        int* __restrict__ cursor, uint2* __restrict__ bins,
        int* __restrict__ deg, int* __restrict__ csrf) {
    int i = blockIdx.x * 256 + threadIdx.x;
    bool valid = i < E_TOT;
    int s = 0, d = 0;
    if (valid) {
        if (i < N_EDGES) { s = src[i]; d = dst[i]; } else { s = d = i - N_EDGES; }
    }
    int bin = valid ? (d / BIN_NODES) : -1;
    int lane = threadIdx.x & 63;
    u64 below = (1ULL << lane) - 1ULL;
    #pragma unroll
    for (int b = 0; b < N_BINS; ++b) {
        u64 mask = __ballot(bin == b);
        if (mask == 0ULL) continue;          // ballot is wave-uniform
        int leader = __ffsll((long long)mask) - 1;
        int base = 0;
        if (lane == leader) base = atomicAdd(&cursor[b], __popcll(mask));
        base = __shfl(base, leader);
        if (bin == b) {
            int pos = base + __popcll(mask & below);
            if (pos < BIN_CAP) {
                bins[(size_t)b * BIN_CAP + pos] = make_uint2((u32)s, (u32)d);
            } else {  // statistically impossible overflow: direct scatter
                int r = atomicAdd(&deg[d], 1);
                if (r < CSR_W) csrf[d * CSR_W + r] = s;
            }
        }
    }
}

// ---------------- CSR build phase B: per-XCD L2-resident scatter ----------------
// bin = blockIdx%8 -> XCD round-robin pins each 3.2MB csrf slice to one XCD's L2.
__global__ __launch_bounds__(256) void binB_kernel(
        const uint2* __restrict__ bins, const int* __restrict__ cursor,
        int* __restrict__ deg, int* __restrict__ csrf) {
    int b   = blockIdx.x & 7;
    int grp = blockIdx.x >> 3;      // 0..255
    int n = cursor[b];
    if (n > BIN_CAP) n = BIN_CAP;
    const uint2* bp = bins + (size_t)b * BIN_CAP;
    for (int i = grp * 256 + threadIdx.x; i < n; i += 256 * 256) {
        uint2 e = bp[i];
        int d = (int)e.y;
        int r = atomicAdd(&deg[d], 1);
        if (r < CSR_W) csrf[d * CSR_W + r] = (int)e.x;
    }
}

// ---------------- MFMA GEMM: Hb(bf16) = X @ W, als = H.a_src, ald = H.a_dst -------
__global__ __launch_bounds__(256) void gemm_kernel(
        const float* __restrict__ X, const float* __restrict__ Wl,
        const float* __restrict__ asr, const float* __restrict__ ads,
        u16* __restrict__ Hb, float* __restrict__ als, float* __restrict__ ald) {
    __shared__ u16 xa[128][136];   // X tile, bf16, row-major [row][k]
    __shared__ u16 wt[128][136];   // W^T,   bf16, [col][k]
    int tid = threadIdx.x;
    int row0 = blockIdx.x * 128;

    #pragma unroll
    for (int i = 0; i < 16; ++i) {
        int e = (i * 256 + tid) * 4;
        int r = e >> 7, c = e & 127;
        int row = row0 + r;
        float4 v = make_float4(0.f, 0.f, 0.f, 0.f);
        if (row < N_NODES) v = *(const float4*)&X[(size_t)row * D + c];
        u32 lo = (u32)f2bf(v.x) | ((u32)f2bf(v.y) << 16);
        u32 hi = (u32)f2bf(v.z) | ((u32)f2bf(v.w) << 16);
        *(uint2*)&xa[r][c] = make_uint2(lo, hi);
    }
    #pragma unroll
    for (int i = 0; i < 16; ++i) {
        int e = (i * 256 + tid) * 4;
        int k = e >> 7, c = e & 127;
        float4 v = *(const float4*)&Wl[e];
        wt[c + 0][k] = f2bf(v.x);
        wt[c + 1][k] = f2bf(v.y);
        wt[c + 2][k] = f2bf(v.z);
        wt[c + 3][k] = f2bf(v.w);
    }
    __syncthreads();

    int wv   = tid >> 6;
    int lane = tid & 63;
    int r16  = lane & 15;
    int g    = lane >> 4;
    int rbase = wv * 32;

    f32x4 acc[2][8];
    #pragma unroll
    for (int rt = 0; rt < 2; ++rt)
        #pragma unroll
        for (int ct = 0; ct < 8; ++ct) acc[rt][ct] = (f32x4){0.f, 0.f, 0.f, 0.f};

    #pragma unroll
    for (int kk = 0; kk < 4; ++kk) {
        int k0 = kk * 32 + g * 8;
        bf16x8 bx0 = *(const bf16x8*)&xa[rbase + r16][k0];
        bf16x8 bx1 = *(const bf16x8*)&xa[rbase + 16 + r16][k0];
        #pragma unroll
        for (int ct = 0; ct < 8; ++ct) {
            bf16x8 aw = *(const bf16x8*)&wt[ct * 16 + r16][k0];
            acc[0][ct] = __builtin_amdgcn_mfma_f32_16x16x32_bf16(aw, bx0, acc[0][ct], 0, 0, 0);
            acc[1][ct] = __builtin_amdgcn_mfma_f32_16x16x32_bf16(aw, bx1, acc[1][ct], 0, 0, 0);
        }
    }

    #pragma unroll
    for (int rt = 0; rt < 2; ++rt) {
        int row = row0 + rbase + rt * 16 + r16;
        float ps = 0.f, pd = 0.f;
        #pragma unroll
        for (int ct = 0; ct < 8; ++ct) {
            float4 av = *(const float4*)&asr[ct * 16 + g * 4];
            float4 dv = *(const float4*)&ads[ct * 16 + g * 4];
            f32x4 a = acc[rt][ct];
            ps += a[0] * av.x + a[1] * av.y + a[2] * av.z + a[3] * av.w;
            pd += a[0] * dv.x + a[1] * dv.y + a[2] * dv.z + a[3] * dv.w;
        }
        ps += __shfl_xor(ps, 16); ps += __shfl_xor(ps, 32);
        pd += __shfl_xor(pd, 16); pd += __shfl_xor(pd, 32);
        if (row < N_NODES) {
            #pragma unroll
            for (int ct = 0; ct < 8; ++ct) {
                f32x4 a = acc[rt][ct];
                u32 lo = (u32)f2bf(a[0]) | ((u32)f2bf(a[1]) << 16);
                u32 hi = (u32)f2bf(a[2]) | ((u32)f2bf(a[3]) << 16);
                *(uint2*)&Hb[(size_t)row * D + ct * 16 + g * 4] = make_uint2(lo, hi);
            }
            if (g == 0) { als[row] = ps; ald[row] = pd; }
        }
    }
}

// ---------------- Edge softmax + aggregate: one wave per dst node ----------------
__global__ __launch_bounds__(256) void edge_kernel(
        const u16* __restrict__ hb, const float* __restrict__ als,
        const float* __restrict__ ald, const int* __restrict__ deg_arr,
        const int* __restrict__ csrf, const float* __restrict__ bias,
        const int* __restrict__ esrc, const int* __restrict__ edst,
        float* __restrict__ out) {
    int gtid = blockIdx.x * blockDim.x + threadIdx.x;
    int node = gtid >> 6;
    int lane = threadIdx.x & 63;
    if (node >= N_NODES) return;
    int deg = deg_arr[node];
    float ad = ald[node];
    float accx = 0.f, accy = 0.f;
    const u16* hl = hb + lane * 2;

    if (deg <= CSR_W) {
        int sreg = 0;
        float v = -3.0e38f;
        if (lane < deg) {
            sreg = csrf[node * CSR_W + lane];
            float t = als[sreg] + ad;
            v = (t > 0.f) ? t : NEG_SLOPE * t;
        }
        float m = v;
        #pragma unroll
        for (int o = 1; o < 64; o <<= 1) m = fmaxf(m, __shfl_xor(m, o));
        float w = (lane < deg) ? __expf(v - m) : 0.f;
        float sum = w;
        #pragma unroll
        for (int o = 1; o < 64; o <<= 1) sum += __shfl_xor(sum, o);
        w *= 1.f / sum;

        int e = 0;
        for (; e + 8 <= deg; e += 8) {
            int s[8]; float wv[8]; ushort2 hv[8];
            #pragma unroll
            for (int k = 0; k < 8; ++k) { s[k] = __shfl(sreg, e + k); wv[k] = __shfl(w, e + k); }
            #pragma unroll
            for (int k = 0; k < 8; ++k) hv[k] = *(const ushort2*)(hl + (size_t)s[k] * D);
            #pragma unroll
            for (int k = 0; k < 8; ++k) {
                accx += wv[k] * bf2f(hv[k].x);
                accy += wv[k] * bf2f(hv[k].y);
            }
        }
        for (; e < deg; ++e) {
            int s0 = __shfl(sreg, e);
            float w0 = __shfl(w, e);
            ushort2 h0 = *(const ushort2*)(hl + (size_t)s0 * D);
            accx += w0 * bf2f(h0.x);
            accy += w0 * bf2f(h0.y);
        }
    } else {
        // overflow fallback (deg > CSR_W): scan the raw edge list.
        float lm = -3.0e38f;
        for (int j = lane; j < E_TOT; j += 64) {
            int d = (j < N_EDGES) ? edst[j] : (j - N_EDGES);
            if (d == node) {
                int s = (j < N_EDGES) ? esrc[j] : (j - N_EDGES);
                float t = als[s] + ad;
                t = (t > 0.f) ? t : NEG_SLOPE * t;
                lm = fmaxf(lm, t);
            }
        }
        #pragma unroll
        for (int o = 1; o < 64; o <<= 1) lm = fmaxf(lm, __shfl_xor(lm, o));
        float m = lm;
        float lsum = 0.f;
        for (int j = lane; j < E_TOT; j += 64) {
            int d = (j < N_EDGES) ? edst[j] : (j - N_EDGES);
            if (d == node) {
                int s = (j < N_EDGES) ? esrc[j] : (j - N_EDGES);
                float t = als[s] + ad;
                t = (t > 0.f) ? t : NEG_SLOPE * t;
                lsum += __expf(t - m);
            }
        }
        #pragma unroll
        for (int o = 1; o < 64; o <<= 1) lsum += __shfl_xor(lsum, o);
        float invden = 1.f / lsum;
        for (int base = 0; base < E_TOT; base += 64) {
            int j = base + lane;
            int d = -1;
            if (j < E_TOT) d = (j < N_EDGES) ? edst[j] : (j - N_EDGES);
            unsigned long long mask = __ballot(d == node);
            while (mask) {
                int b = __ffsll(mask) - 1;
                mask &= mask - 1;
                int jj = base + b;
                int s = (jj < N_EDGES) ? esrc[jj] : (jj - N_EDGES);
                float t = als[s] + ad;
                t = (t > 0.f) ? t : NEG_SLOPE * t;
                float w = __expf(t - m) * invden;
                ushort2 hv = *(const ushort2*)(hl + (size_t)s * D);
                accx += w * bf2f(hv.x);
                accy += w * bf2f(hv.y);
            }
        }
    }

    float2 bv = *(const float2*)(bias + lane * 2);
    *(float2*)(out + (size_t)node * D + lane * 2) = make_float2(accx + bv.x, accy + bv.y);
}

// ---------------- Pooling + readout ----------------
__global__ void bounds_kernel(const int* __restrict__ batch, int* __restrict__ gstart) {
    int g = blockIdx.x * blockDim.x + threadIdx.x;
    if (g > N_GRAPHS) return;
    if (g == N_GRAPHS) { gstart[g] = N_NODES; return; }
    int lo = 0, hi = N_NODES;
    while (lo < hi) { int mid = (lo + hi) >> 1; if (batch[mid] < g) lo = mid + 1; else hi = mid; }
    gstart[g] = lo;
}

__global__ void pool_kernel(const float* __restrict__ x, const int* __restrict__ gstart,
                            float* __restrict__ gpool) {
    int g = blockIdx.x >> 3, c = blockIdx.x & 7;
    int t = threadIdx.x;
    int beg = gstart[g], end = gstart[g + 1];
    float acc = 0.f;
    for (int i = beg + c; i < end; i += 8) acc += x[(size_t)i * D + t];
    atomicAdd(&gpool[g * D + t], acc);
}

__global__ void readout_kernel(const float* __restrict__ gpool,
                               const float* __restrict__ W1, const float* __restrict__ b1,
                               const float* __restrict__ W2, const float* __restrict__ b2,
                               float* __restrict__ out) {
    int g = blockIdx.x;
    int t = threadIdx.x;   // 64 threads
    __shared__ float hid[64];
    float a = b1[t];
    for (int k = 0; k < D; ++k) a += gpool[g * D + k] * W1[k * 64 + t];
    hid[t] = fmaxf(a, 0.f);
    __syncthreads();
    if (t < N_TARGETS) {
        float o = b2[t];
        for (int k = 0; k < 64; ++k) o += hid[k] * W2[k * N_TARGETS + t];
        out[g * N_TARGETS + t] = o;
    }
}

extern "C" void kernel_launch(void* const* d_in, const int* in_sizes, int n_in,
                              void* d_out, int out_size, void* d_ws, size_t ws_size,
                              hipStream_t stream) {
    const float* x    = (const float*)d_in[0];
    const int*   ei   = (const int*)d_in[1];
    const int*   batch= (const int*)d_in[2];
    const float* W    = (const float*)d_in[3];
    const float* a_s  = (const float*)d_in[4];
    const float* a_d  = (const float*)d_in[5];
    const float* bias = (const float*)d_in[6];
    const float* W1   = (const float*)d_in[7];
    const float* b1   = (const float*)d_in[8];
    const float* W2   = (const float*)d_in[9];
    const float* b2   = (const float*)d_in[10];
    float* out = (float*)d_out;
    const int* srcp = ei;
    const int* dstp = ei + N_EDGES;

    char* p = (char*)d_ws;
    float* bufA = (float*)p; p += (size_t)N_NODES * D * 4;      // 51.2 MB
    float* bufB = (float*)p; p += (size_t)N_NODES * D * 4;      // 51.2 MB (bins alias here)
    u16* hb     = (u16*)p;   p += (size_t)N_NODES * D * 2;      // 25.6 MB
    int* csrf   = (int*)p;   p += (size_t)N_NODES * CSR_W * 4;  // 25.6 MB
    float* als  = (float*)p; p += (size_t)N_NODES * 4;
    float* ald  = (float*)p; p += (size_t)N_NODES * 4;
    int* deg    = (int*)p;   p += (size_t)N_NODES * 4;
    int* cursor = (int*)p;   p += 64;
    int* gstart = (int*)p;   p += 132 * 4;
    float* gpool = (float*)p; p += N_GRAPHS * D * 4;
    uint2* bins = (uint2*)bufB;   // 8*400000*8B = 25.6 MB, dead until layer-1 edge out

    hipMemsetAsync(deg, 0, N_NODES * 4, stream);
    hipMemsetAsync(cursor, 0, 64, stream);
    hipMemsetAsync(gpool, 0, N_GRAPHS * D * 4, stream);

    int eb = (E_TOT + 255) / 256;
    binA_kernel<<<eb, 256, 0, stream>>>(srcp, dstp, cursor, bins, deg, csrf);
    binB_kernel<<<2048, 256, 0, stream>>>(bins, cursor, deg, csrf);
    bounds_kernel<<<1, 256, 0, stream>>>(batch, gstart);

    const float* cur = x;
    float* outs[3] = {bufA, bufB, bufA};
    for (int l = 0; l < N_LAYERS; ++l) {
        gemm_kernel<<<(N_NODES + 127) / 128, 256, 0, stream>>>(
            cur, W + (size_t)l * D * D, a_s + (size_t)l * D, a_d + (size_t)l * D,
            hb, als, ald);
        edge_kernel<<<(N_NODES * 64 + 255) / 256, 256, 0, stream>>>(
            hb, als, ald, deg, csrf, bias + (size_t)l * D, srcp, dstp, outs[l]);
        cur = outs[l];
    }
    pool_kernel<<<N_GRAPHS * 8, 128, 0, stream>>>(cur, gstart, gpool);
    readout_kernel<<<N_GRAPHS, 64, 0, stream>>>(gpool, W1, b1, W2, b2, out);
}

// Round 13
// 591.218 us; speedup vs baseline: 4.8249x; 4.8249x over previous
//
#include <hip/hip_runtime.h>
#include <math.h>

#define N_NODES 100000
#define N_EDGES 1600000
#define D 128
#define N_LAYERS 3
#define N_GRAPHS 128
#define N_TARGETS 10
#define NEG_SLOPE 0.2f
#define E_TOT (N_EDGES + N_NODES)
#define CSR_W 64   /* fixed-width CSR rows; deg>64 handled by fallback scan */

typedef unsigned int u32;
typedef unsigned short u16;
typedef __attribute__((ext_vector_type(8))) short bf16x8;
typedef __attribute__((ext_vector_type(4))) float f32x4;

__device__ __forceinline__ float bf2f(u16 b) {
    u32 u = ((u32)b) << 16;
    return __uint_as_float(u);
}
__device__ __forceinline__ u16 f2bf(float f) {  // round-to-nearest-even
    u32 u = __float_as_uint(f);
    u32 r = (u + 0x7fffu + ((u >> 16) & 1u)) >> 16;
    return (u16)r;
}

// ---------------- CSR build, transposed slabs ----------------
// csrf2[r*N + d]: slot-r writes concentrate in a dense 400KB slab so L2 lines
// absorb multiple same-slab writes before eviction (vs 64B write-allocate per
// 4B scatter in the [d][r] layout). deg atomics distributed over 100K words.
__global__ void build_t_kernel(const int* __restrict__ src, const int* __restrict__ dst,
                               int* __restrict__ deg, int* __restrict__ csrf2) {
    int i = blockIdx.x * blockDim.x + threadIdx.x;
    if (i >= E_TOT) return;
    int s, d;
    if (i < N_EDGES) { s = src[i]; d = dst[i]; } else { s = d = i - N_EDGES; }
    int r = atomicAdd(&deg[d], 1);
    if (r < CSR_W) csrf2[(size_t)r * N_NODES + d] = s;
}

// ---------------- repack: csrf2[r][d] -> csrf[d][r], LDS transpose ----------------
// 64-node x 64-slot tile = 4096 ints per block.
// Read:  16 iters x 256 threads x 1 int   = 4096  (coalesced rows of csrf2)
// Write:  4 iters x 256 threads x 1 int4  = 4096  (coalesced rows of csrf)
// (round-12 crash: write loop ran 16 iters -> LDS OOB + cross-block garbage)
__global__ __launch_bounds__(256) void repack_kernel(const int* __restrict__ csrf2,
                                                     int* __restrict__ csrf) {
    __shared__ int t[64][67];
    int d0 = blockIdx.x * 64;
    int tid = threadIdx.x;
    #pragma unroll
    for (int it = 0; it < 16; ++it) {
        int idx = it * 256 + tid;
        int r = idx >> 6, n = idx & 63;
        int d = d0 + n;
        t[r][n] = (d < N_NODES) ? csrf2[(size_t)r * N_NODES + d] : 0;
    }
    __syncthreads();
    #pragma unroll
    for (int it = 0; it < 4; ++it) {
        int idx = it * 256 + tid;      // 0..1023
        int n = idx >> 4, q = idx & 15;  // n: 0..63 node-in-tile, q: int4 index
        int d = d0 + n;
        if (d < N_NODES) {
            int4 v = make_int4(t[4 * q + 0][n], t[4 * q + 1][n],
                               t[4 * q + 2][n], t[4 * q + 3][n]);
            *(int4*)&csrf[(size_t)d * CSR_W + 4 * q] = v;
        }
    }
}

// ---------------- MFMA GEMM: Hb(bf16) = X @ W, als = H.a_src, ald = H.a_dst -------
__global__ __launch_bounds__(256) void gemm_kernel(
        const float* __restrict__ X, const float* __restrict__ Wl,
        const float* __restrict__ asr, const float* __restrict__ ads,
        u16* __restrict__ Hb, float* __restrict__ als, float* __restrict__ ald) {
    __shared__ u16 xa[128][136];   // X tile, bf16, row-major [row][k]
    __shared__ u16 wt[128][136];   // W^T,   bf16, [col][k]
    int tid = threadIdx.x;
    int row0 = blockIdx.x * 128;

    #pragma unroll
    for (int i = 0; i < 16; ++i) {
        int e = (i * 256 + tid) * 4;
        int r = e >> 7, c = e & 127;
        int row = row0 + r;
        float4 v = make_float4(0.f, 0.f, 0.f, 0.f);
        if (row < N_NODES) v = *(const float4*)&X[(size_t)row * D + c];
        u32 lo = (u32)f2bf(v.x) | ((u32)f2bf(v.y) << 16);
        u32 hi = (u32)f2bf(v.z) | ((u32)f2bf(v.w) << 16);
        *(uint2*)&xa[r][c] = make_uint2(lo, hi);
    }
    #pragma unroll
    for (int i = 0; i < 16; ++i) {
        int e = (i * 256 + tid) * 4;
        int k = e >> 7, c = e & 127;
        float4 v = *(const float4*)&Wl[e];
        wt[c + 0][k] = f2bf(v.x);
        wt[c + 1][k] = f2bf(v.y);
        wt[c + 2][k] = f2bf(v.z);
        wt[c + 3][k] = f2bf(v.w);
    }
    __syncthreads();

    int wv   = tid >> 6;
    int lane = tid & 63;
    int r16  = lane & 15;
    int g    = lane >> 4;
    int rbase = wv * 32;

    f32x4 acc[2][8];
    #pragma unroll
    for (int rt = 0; rt < 2; ++rt)
        #pragma unroll
        for (int ct = 0; ct < 8; ++ct) acc[rt][ct] = (f32x4){0.f, 0.f, 0.f, 0.f};

    #pragma unroll
    for (int kk = 0; kk < 4; ++kk) {
        int k0 = kk * 32 + g * 8;
        bf16x8 bx0 = *(const bf16x8*)&xa[rbase + r16][k0];
        bf16x8 bx1 = *(const bf16x8*)&xa[rbase + 16 + r16][k0];
        #pragma unroll
        for (int ct = 0; ct < 8; ++ct) {
            bf16x8 aw = *(const bf16x8*)&wt[ct * 16 + r16][k0];
            acc[0][ct] = __builtin_amdgcn_mfma_f32_16x16x32_bf16(aw, bx0, acc[0][ct], 0, 0, 0);
            acc[1][ct] = __builtin_amdgcn_mfma_f32_16x16x32_bf16(aw, bx1, acc[1][ct], 0, 0, 0);
        }
    }

    #pragma unroll
    for (int rt = 0; rt < 2; ++rt) {
        int row = row0 + rbase + rt * 16 + r16;
        float ps = 0.f, pd = 0.f;
        #pragma unroll
        for (int ct = 0; ct < 8; ++ct) {
            float4 av = *(const float4*)&asr[ct * 16 + g * 4];
            float4 dv = *(const float4*)&ads[ct * 16 + g * 4];
            f32x4 a = acc[rt][ct];
            ps += a[0] * av.x + a[1] * av.y + a[2] * av.z + a[3] * av.w;
            pd += a[0] * dv.x + a[1] * dv.y + a[2] * dv.z + a[3] * dv.w;
        }
        ps += __shfl_xor(ps, 16); ps += __shfl_xor(ps, 32);
        pd += __shfl_xor(pd, 16); pd += __shfl_xor(pd, 32);
        if (row < N_NODES) {
            #pragma unroll
            for (int ct = 0; ct < 8; ++ct) {
                f32x4 a = acc[rt][ct];
                u32 lo = (u32)f2bf(a[0]) | ((u32)f2bf(a[1]) << 16);
                u32 hi = (u32)f2bf(a[2]) | ((u32)f2bf(a[3]) << 16);
                *(uint2*)&Hb[(size_t)row * D + ct * 16 + g * 4] = make_uint2(lo, hi);
            }
            if (g == 0) { als[row] = ps; ald[row] = pd; }
        }
    }
}

// ---------------- Edge softmax + aggregate: one wave per dst node ----------------
__global__ __launch_bounds__(256) void edge_kernel(
        const u16* __restrict__ hb, const float* __restrict__ als,
        const float* __restrict__ ald, const int* __restrict__ deg_arr,
        const int* __restrict__ csrf, const float* __restrict__ bias,
        const int* __restrict__ esrc, const int* __restrict__ edst,
        float* __restrict__ out) {
    int gtid = blockIdx.x * blockDim.x + threadIdx.x;
    int node = gtid >> 6;
    int lane = threadIdx.x & 63;
    if (node >= N_NODES) return;
    int deg = deg_arr[node];
    float ad = ald[node];
    float accx = 0.f, accy = 0.f;
    const u16* hl = hb + lane * 2;

    if (deg <= CSR_W) {
        int sreg = 0;
        float v = -3.0e38f;
        if (lane < deg) {
            sreg = csrf[node * CSR_W + lane];
            float t = als[sreg] + ad;
            v = (t > 0.f) ? t : NEG_SLOPE * t;
        }
        float m = v;
        #pragma unroll
        for (int o = 1; o < 64; o <<= 1) m = fmaxf(m, __shfl_xor(m, o));
        float w = (lane < deg) ? __expf(v - m) : 0.f;
        float sum = w;
        #pragma unroll
        for (int o = 1; o < 64; o <<= 1) sum += __shfl_xor(sum, o);
        w *= 1.f / sum;

        int e = 0;
        for (; e + 8 <= deg; e += 8) {
            int s[8]; float wv[8]; ushort2 hv[8];
            #pragma unroll
            for (int k = 0; k < 8; ++k) { s[k] = __shfl(sreg, e + k); wv[k] = __shfl(w, e + k); }
            #pragma unroll
            for (int k = 0; k < 8; ++k) hv[k] = *(const ushort2*)(hl + (size_t)s[k] * D);
            #pragma unroll
            for (int k = 0; k < 8; ++k) {
                accx += wv[k] * bf2f(hv[k].x);
                accy += wv[k] * bf2f(hv[k].y);
            }
        }
        for (; e < deg; ++e) {
            int s0 = __shfl(sreg, e);
            float w0 = __shfl(w, e);
            ushort2 h0 = *(const ushort2*)(hl + (size_t)s0 * D);
            accx += w0 * bf2f(h0.x);
            accy += w0 * bf2f(h0.y);
        }
    } else {
        // overflow fallback (deg > CSR_W): scan the raw edge list.
        float lm = -3.0e38f;
        for (int j = lane; j < E_TOT; j += 64) {
            int d = (j < N_EDGES) ? edst[j] : (j - N_EDGES);
            if (d == node) {
                int s = (j < N_EDGES) ? esrc[j] : (j - N_EDGES);
                float t = als[s] + ad;
                t = (t > 0.f) ? t : NEG_SLOPE * t;
                lm = fmaxf(lm, t);
            }
        }
        #pragma unroll
        for (int o = 1; o < 64; o <<= 1) lm = fmaxf(lm, __shfl_xor(lm, o));
        float m = lm;
        float lsum = 0.f;
        for (int j = lane; j < E_TOT; j += 64) {
            int d = (j < N_EDGES) ? edst[j] : (j - N_EDGES);
            if (d == node) {
                int s = (j < N_EDGES) ? esrc[j] : (j - N_EDGES);
                float t = als[s] + ad;
                t = (t > 0.f) ? t : NEG_SLOPE * t;
                lsum += __expf(t - m);
            }
        }
        #pragma unroll
        for (int o = 1; o < 64; o <<= 1) lsum += __shfl_xor(lsum, o);
        float invden = 1.f / lsum;
        for (int base = 0; base < E_TOT; base += 64) {
            int j = base + lane;
            int d = -1;
            if (j < E_TOT) d = (j < N_EDGES) ? edst[j] : (j - N_EDGES);
            unsigned long long mask = __ballot(d == node);
            while (mask) {
                int b = __ffsll(mask) - 1;
                mask &= mask - 1;
                int jj = base + b;
                int s = (jj < N_EDGES) ? esrc[jj] : (jj - N_EDGES);
                float t = als[s] + ad;
                t = (t > 0.f) ? t : NEG_SLOPE * t;
                float w = __expf(t - m) * invden;
                ushort2 hv = *(const ushort2*)(hl + (size_t)s * D);
                accx += w * bf2f(hv.x);
                accy += w * bf2f(hv.y);
            }
        }
    }

    float2 bv = *(const float2*)(bias + lane * 2);
    *(float2*)(out + (size_t)node * D + lane * 2) = make_float2(accx + bv.x, accy + bv.y);
}

// ---------------- Pooling + readout ----------------
__global__ void bounds_kernel(const int* __restrict__ batch, int* __restrict__ gstart) {
    int g = blockIdx.x * blockDim.x + threadIdx.x;
    if (g > N_GRAPHS) return;
    if (g == N_GRAPHS) { gstart[g] = N_NODES; return; }
    int lo = 0, hi = N_NODES;
    while (lo < hi) { int mid = (lo + hi) >> 1; if (batch[mid] < g) lo = mid + 1; else hi = mid; }
    gstart[g] = lo;
}

__global__ void pool_kernel(const float* __restrict__ x, const int* __restrict__ gstart,
                            float* __restrict__ gpool) {
    int g = blockIdx.x >> 3, c = blockIdx.x & 7;
    int t = threadIdx.x;
    int beg = gstart[g], end = gstart[g + 1];
    float acc = 0.f;
    for (int i = beg + c; i < end; i += 8) acc += x[(size_t)i * D + t];
    atomicAdd(&gpool[g * D + t], acc);
}

__global__ void readout_kernel(const float* __restrict__ gpool,
                               const float* __restrict__ W1, const float* __restrict__ b1,
                               const float* __restrict__ W2, const float* __restrict__ b2,
                               float* __restrict__ out) {
    int g = blockIdx.x;
    int t = threadIdx.x;   // 64 threads
    __shared__ float hid[64];
    float a = b1[t];
    for (int k = 0; k < D; ++k) a += gpool[g * D + k] * W1[k * 64 + t];
    hid[t] = fmaxf(a, 0.f);
    __syncthreads();
    if (t < N_TARGETS) {
        float o = b2[t];
        for (int k = 0; k < 64; ++k) o += hid[k] * W2[k * N_TARGETS + t];
        out[g * N_TARGETS + t] = o;
    }
}

extern "C" void kernel_launch(void* const* d_in, const int* in_sizes, int n_in,
                              void* d_out, int out_size, void* d_ws, size_t ws_size,
                              hipStream_t stream) {
    const float* x    = (const float*)d_in[0];
    const int*   ei   = (const int*)d_in[1];
    const int*   batch= (const int*)d_in[2];
    const float* W    = (const float*)d_in[3];
    const float* a_s  = (const float*)d_in[4];
    const float* a_d  = (const float*)d_in[5];
    const float* bias = (const float*)d_in[6];
    const float* W1   = (const float*)d_in[7];
    const float* b1   = (const float*)d_in[8];
    const float* W2   = (const float*)d_in[9];
    const float* b2   = (const float*)d_in[10];
    float* out = (float*)d_out;
    const int* srcp = ei;
    const int* dstp = ei + N_EDGES;

    char* p = (char*)d_ws;
    float* bufA = (float*)p; p += (size_t)N_NODES * D * 4;      // 51.2 MB
    float* bufB = (float*)p; p += (size_t)N_NODES * D * 4;      // 51.2 MB (csrf2 aliases)
    u16* hb     = (u16*)p;   p += (size_t)N_NODES * D * 2;      // 25.6 MB
    int* csrf   = (int*)p;   p += (size_t)N_NODES * CSR_W * 4;  // 25.6 MB
    float* als  = (float*)p; p += (size_t)N_NODES * 4;
    float* ald  = (float*)p; p += (size_t)N_NODES * 4;
    int* deg    = (int*)p;   p += (size_t)N_NODES * 4;
    int* gstart = (int*)p;   p += 132 * 4;
    float* gpool = (float*)p; p += N_GRAPHS * D * 4;
    int* csrf2 = (int*)bufB;   // 25.6 MB, dead until layer-1 edge output

    hipMemsetAsync(deg, 0, N_NODES * 4, stream);
    hipMemsetAsync(gpool, 0, N_GRAPHS * D * 4, stream);

    int eb = (E_TOT + 255) / 256;
    build_t_kernel<<<eb, 256, 0, stream>>>(srcp, dstp, deg, csrf2);
    repack_kernel<<<(N_NODES + 63) / 64, 256, 0, stream>>>(csrf2, csrf);
    bounds_kernel<<<1, 256, 0, stream>>>(batch, gstart);

    const float* cur = x;
    float* outs[3] = {bufA, bufB, bufA};
    for (int l = 0; l < N_LAYERS; ++l) {
        gemm_kernel<<<(N_NODES + 127) / 128, 256, 0, stream>>>(
            cur, W + (size_t)l * D * D, a_s + (size_t)l * D, a_d + (size_t)l * D,
            hb, als, ald);
        edge_kernel<<<(N_NODES * 64 + 255) / 256, 256, 0, stream>>>(
            hb, als, ald, deg, csrf, bias + (size_t)l * D, srcp, dstp, outs[l]);
        cur = outs[l];
    }
    pool_kernel<<<N_GRAPHS * 8, 128, 0, stream>>>(cur, gstart, gpool);
    readout_kernel<<<N_GRAPHS, 64, 0, stream>>>(gpool, W1, b1, W2, b2, out);
}

// Round 14
// 562.824 us; speedup vs baseline: 5.0684x; 1.0504x over previous
//
#include <hip/hip_runtime.h>
#include <math.h>

#define N_NODES 100000
#define N_EDGES 1600000
#define D 128
#define N_LAYERS 3
#define N_GRAPHS 128
#define N_TARGETS 10
#define NEG_SLOPE 0.2f
#define E_TOT (N_EDGES + N_NODES)

#define NBK 256          /* dst buckets */
#define BKT_NODES 391    /* ceil(N_NODES/NBK) */
#define CHUNK 6641       /* ceil(E_TOT/256) edges per pass-A block */
#define SEG_CAP 8192     /* LDS row-build capacity per bucket (mean 6641, sigma~80) */

typedef unsigned int u32;
typedef unsigned short u16;
typedef __attribute__((ext_vector_type(8))) short bf16x8;
typedef __attribute__((ext_vector_type(4))) float f32x4;

__device__ __forceinline__ float bf2f(u16 b) {
    u32 u = ((u32)b) << 16;
    return __uint_as_float(u);
}
__device__ __forceinline__ u16 f2bf(float f) {  // round-to-nearest-even
    u32 u = __float_as_uint(f);
    u32 r = (u + 0x7fffu + ((u >> 16) & 1u)) >> 16;
    return (u16)r;
}

// ---------------- CSR build A1: per-block bucket histogram ----------------
__global__ __launch_bounds__(256) void histA_kernel(const int* __restrict__ dst,
                                                    int* __restrict__ cntg) {
    __shared__ int c[NBK];
    int blk = blockIdx.x, tid = threadIdx.x;
    c[tid] = 0;
    __syncthreads();
    int base = blk * CHUNK;
    int end = base + CHUNK; if (end > E_TOT) end = E_TOT;
    for (int i = base + tid; i < end; i += 256) {
        int d = (i < N_EDGES) ? dst[i] : (i - N_EDGES);
        atomicAdd(&c[d / BKT_NODES], 1);
    }
    __syncthreads();
    cntg[blk * NBK + tid] = c[tid];   // coalesced
}

// ---------------- CSR build A2: exact offsets (one block, no global atomics) ----
__global__ __launch_bounds__(256) void scanA_kernel(int* __restrict__ cntg,
                                                    int* __restrict__ bucket_base) {
    __shared__ int tot[NBK];
    __shared__ int sc[NBK];
    int b = threadIdx.x;
    int sum = 0;
    for (int blk = 0; blk < 256; ++blk) {        // coalesced across threads
        int v = cntg[blk * NBK + b];
        cntg[blk * NBK + b] = sum;               // exclusive prefix within bucket
        sum += v;
    }
    tot[b] = sum;
    sc[b] = sum;
    __syncthreads();
    for (int o = 1; o < NBK; o <<= 1) {
        int x = (b >= o) ? sc[b - o] : 0;
        __syncthreads();
        sc[b] += x;
        __syncthreads();
    }
    int excl = sc[b] - tot[b];
    bucket_base[b] = excl;
    if (b == NBK - 1) bucket_base[NBK] = excl + tot[b];
    for (int blk = 0; blk < 256; ++blk) cntg[blk * NBK + b] += excl;  // absolute
}

// ---------------- CSR build A3: scatter pairs bucket-grouped ----------------
__global__ __launch_bounds__(256) void scatA_kernel(const int* __restrict__ src,
                                                    const int* __restrict__ dst,
                                                    const int* __restrict__ cntg,
                                                    uint2* __restrict__ tmp) {
    __shared__ int off[NBK];
    __shared__ int c2[NBK];
    int blk = blockIdx.x, tid = threadIdx.x;
    off[tid] = cntg[blk * NBK + tid];
    c2[tid] = 0;
    __syncthreads();
    int base = blk * CHUNK;
    int end = base + CHUNK; if (end > E_TOT) end = E_TOT;
    for (int i = base + tid; i < end; i += 256) {
        int s, d;
        if (i < N_EDGES) { s = src[i]; d = dst[i]; } else { s = d = i - N_EDGES; }
        int b = d / BKT_NODES;
        int r = atomicAdd(&c2[b], 1);
        tmp[off[b] + r] = make_uint2((u32)s, (u32)d);
    }
}

// ---------------- CSR build B: per-bucket node sort, coalesced CSR write --------
__global__ __launch_bounds__(256) void bucketB_kernel(const uint2* __restrict__ tmp,
                                                      const int* __restrict__ bucket_base,
                                                      int* __restrict__ offg,
                                                      int* __restrict__ csr) {
    __shared__ int dcnt[BKT_NODES + 1];
    __shared__ int lro[BKT_NODES + 1];
    __shared__ int psum[256];
    __shared__ int srow[SEG_CAP];
    int b = blockIdx.x, tid = threadIdx.x;
    int dbase = b * BKT_NODES;
    int nb = N_NODES - dbase; if (nb > BKT_NODES) nb = BKT_NODES;
    int beg = bucket_base[b], end = bucket_base[b + 1];
    int len = end - beg;

    for (int i = tid; i < BKT_NODES + 1; i += 256) dcnt[i] = 0;
    __syncthreads();
    for (int i = tid; i < len; i += 256) {
        uint2 e = tmp[beg + i];
        atomicAdd(&dcnt[(int)e.y - dbase], 1);
    }
    __syncthreads();
    // exclusive scan of dcnt[0..nb) -> lro (pair-sum + 256-wide Hillis-Steele)
    int a0 = (2 * tid     < nb) ? dcnt[2 * tid]     : 0;
    int a1 = (2 * tid + 1 < nb) ? dcnt[2 * tid + 1] : 0;
    psum[tid] = a0 + a1;
    __syncthreads();
    for (int o = 1; o < 256; o <<= 1) {
        int x = (tid >= o) ? psum[tid - o] : 0;
        __syncthreads();
        psum[tid] += x;
        __syncthreads();
    }
    int excl = psum[tid] - (a0 + a1);
    if (2 * tid     < nb) lro[2 * tid]     = excl;
    if (2 * tid + 1 < nb) lro[2 * tid + 1] = excl + a0;
    __syncthreads();
    // global CSR offsets (coalesced)
    for (int i = tid; i < nb; i += 256) offg[dbase + i] = beg + lro[i];
    if (b == 0 && tid == 0) offg[N_NODES] = E_TOT;
    // rank + build rows
    for (int i = tid; i < nb; i += 256) dcnt[i] = 0;
    __syncthreads();
    if (len <= SEG_CAP) {
        for (int i = tid; i < len; i += 256) {
            uint2 e = tmp[beg + i];
            int dl = (int)e.y - dbase;
            int r = atomicAdd(&dcnt[dl], 1);
            srow[lro[dl] + r] = (int)e.x;
        }
        __syncthreads();
        for (int i = tid; i < len; i += 256) csr[beg + i] = srow[i];  // coalesced
    } else {  // freak bucket: correct but scattered
        for (int i = tid; i < len; i += 256) {
            uint2 e = tmp[beg + i];
            int dl = (int)e.y - dbase;
            int r = atomicAdd(&dcnt[dl], 1);
            csr[beg + lro[dl] + r] = (int)e.x;
        }
    }
}

// ---------------- MFMA GEMM: Hb(bf16) = X @ W, als = H.a_src, ald = H.a_dst -------
__global__ __launch_bounds__(256) void gemm_kernel(
        const float* __restrict__ X, const float* __restrict__ Wl,
        const float* __restrict__ asr, const float* __restrict__ ads,
        u16* __restrict__ Hb, float* __restrict__ als, float* __restrict__ ald) {
    __shared__ u16 xa[128][136];   // X tile, bf16, row-major [row][k]
    __shared__ u16 wt[128][136];   // W^T,   bf16, [col][k]
    int tid = threadIdx.x;
    int row0 = blockIdx.x * 128;

    #pragma unroll
    for (int i = 0; i < 16; ++i) {
        int e = (i * 256 + tid) * 4;
        int r = e >> 7, c = e & 127;
        int row = row0 + r;
        float4 v = make_float4(0.f, 0.f, 0.f, 0.f);
        if (row < N_NODES) v = *(const float4*)&X[(size_t)row * D + c];
        u32 lo = (u32)f2bf(v.x) | ((u32)f2bf(v.y) << 16);
        u32 hi = (u32)f2bf(v.z) | ((u32)f2bf(v.w) << 16);
        *(uint2*)&xa[r][c] = make_uint2(lo, hi);
    }
    #pragma unroll
    for (int i = 0; i < 16; ++i) {
        int e = (i * 256 + tid) * 4;
        int k = e >> 7, c = e & 127;
        float4 v = *(const float4*)&Wl[e];
        wt[c + 0][k] = f2bf(v.x);
        wt[c + 1][k] = f2bf(v.y);
        wt[c + 2][k] = f2bf(v.z);
        wt[c + 3][k] = f2bf(v.w);
    }
    __syncthreads();

    int wv   = tid >> 6;
    int lane = tid & 63;
    int r16  = lane & 15;
    int g    = lane >> 4;
    int rbase = wv * 32;

    f32x4 acc[2][8];
    #pragma unroll
    for (int rt = 0; rt < 2; ++rt)
        #pragma unroll
        for (int ct = 0; ct < 8; ++ct) acc[rt][ct] = (f32x4){0.f, 0.f, 0.f, 0.f};

    #pragma unroll
    for (int kk = 0; kk < 4; ++kk) {
        int k0 = kk * 32 + g * 8;
        bf16x8 bx0 = *(const bf16x8*)&xa[rbase + r16][k0];
        bf16x8 bx1 = *(const bf16x8*)&xa[rbase + 16 + r16][k0];
        #pragma unroll
        for (int ct = 0; ct < 8; ++ct) {
            bf16x8 aw = *(const bf16x8*)&wt[ct * 16 + r16][k0];
            acc[0][ct] = __builtin_amdgcn_mfma_f32_16x16x32_bf16(aw, bx0, acc[0][ct], 0, 0, 0);
            acc[1][ct] = __builtin_amdgcn_mfma_f32_16x16x32_bf16(aw, bx1, acc[1][ct], 0, 0, 0);
        }
    }

    #pragma unroll
    for (int rt = 0; rt < 2; ++rt) {
        int row = row0 + rbase + rt * 16 + r16;
        float ps = 0.f, pd = 0.f;
        #pragma unroll
        for (int ct = 0; ct < 8; ++ct) {
            float4 av = *(const float4*)&asr[ct * 16 + g * 4];
            float4 dv = *(const float4*)&ads[ct * 16 + g * 4];
            f32x4 a = acc[rt][ct];
            ps += a[0] * av.x + a[1] * av.y + a[2] * av.z + a[3] * av.w;
            pd += a[0] * dv.x + a[1] * dv.y + a[2] * dv.z + a[3] * dv.w;
        }
        ps += __shfl_xor(ps, 16); ps += __shfl_xor(ps, 32);
        pd += __shfl_xor(pd, 16); pd += __shfl_xor(pd, 32);
        if (row < N_NODES) {
            #pragma unroll
            for (int ct = 0; ct < 8; ++ct) {
                f32x4 a = acc[rt][ct];
                u32 lo = (u32)f2bf(a[0]) | ((u32)f2bf(a[1]) << 16);
                u32 hi = (u32)f2bf(a[2]) | ((u32)f2bf(a[3]) << 16);
                *(uint2*)&Hb[(size_t)row * D + ct * 16 + g * 4] = make_uint2(lo, hi);
            }
            if (g == 0) { als[row] = ps; ald[row] = pd; }
        }
    }
}

// ---------------- Edge softmax + aggregate: one wave per dst node ----------------
__global__ __launch_bounds__(256) void edge_kernel(
        const u16* __restrict__ hb, const float* __restrict__ als,
        const float* __restrict__ ald, const int* __restrict__ off,
        const int* __restrict__ csr, const float* __restrict__ bias,
        float* __restrict__ out) {
    int gtid = blockIdx.x * blockDim.x + threadIdx.x;
    int node = gtid >> 6;
    int lane = threadIdx.x & 63;
    if (node >= N_NODES) return;
    int beg = off[node], end = off[node + 1];
    int deg = end - beg;
    float ad = ald[node];
    float accx = 0.f, accy = 0.f;
    const u16* hl = hb + lane * 2;

    if (deg <= 64) {
        int sreg = 0;
        float v = -3.0e38f;
        if (lane < deg) {
            sreg = csr[beg + lane];
            float t = als[sreg] + ad;
            v = (t > 0.f) ? t : NEG_SLOPE * t;
        }
        float m = v;
        #pragma unroll
        for (int o = 1; o < 64; o <<= 1) m = fmaxf(m, __shfl_xor(m, o));
        float w = (lane < deg) ? __expf(v - m) : 0.f;
        float sum = w;
        #pragma unroll
        for (int o = 1; o < 64; o <<= 1) sum += __shfl_xor(sum, o);
        w *= 1.f / sum;

        int e = 0;
        for (; e + 8 <= deg; e += 8) {
            int s[8]; float wv[8]; ushort2 hv[8];
            #pragma unroll
            for (int k = 0; k < 8; ++k) { s[k] = __shfl(sreg, e + k); wv[k] = __shfl(w, e + k); }
            #pragma unroll
            for (int k = 0; k < 8; ++k) hv[k] = *(const ushort2*)(hl + (size_t)s[k] * D);
            #pragma unroll
            for (int k = 0; k < 8; ++k) {
                accx += wv[k] * bf2f(hv[k].x);
                accy += wv[k] * bf2f(hv[k].y);
            }
        }
        for (; e < deg; ++e) {
            int s0 = __shfl(sreg, e);
            float w0 = __shfl(w, e);
            ushort2 h0 = *(const ushort2*)(hl + (size_t)s0 * D);
            accx += w0 * bf2f(h0.x);
            accy += w0 * bf2f(h0.y);
        }
    } else {
        // generic path over the contiguous CSR segment (any degree)
        float lm = -3.0e38f;
        for (int j = lane; j < deg; j += 64) {
            int s = csr[beg + j];
            float t = als[s] + ad;
            t = (t > 0.f) ? t : NEG_SLOPE * t;
            lm = fmaxf(lm, t);
        }
        #pragma unroll
        for (int o = 1; o < 64; o <<= 1) lm = fmaxf(lm, __shfl_xor(lm, o));
        float m = lm;
        float lsum = 0.f;
        for (int j = lane; j < deg; j += 64) {
            int s = csr[beg + j];
            float t = als[s] + ad;
            t = (t > 0.f) ? t : NEG_SLOPE * t;
            lsum += __expf(t - m);
        }
        #pragma unroll
        for (int o = 1; o < 64; o <<= 1) lsum += __shfl_xor(lsum, o);
        float invden = 1.f / lsum;
        for (int e = 0; e < deg; ++e) {
            int s = csr[beg + e];
            float t = als[s] + ad;
            t = (t > 0.f) ? t : NEG_SLOPE * t;
            float w = __expf(t - m) * invden;
            ushort2 hv = *(const ushort2*)(hl + (size_t)s * D);
            accx += w * bf2f(hv.x);
            accy += w * bf2f(hv.y);
        }
    }

    float2 bv = *(const float2*)(bias + lane * 2);
    *(float2*)(out + (size_t)node * D + lane * 2) = make_float2(accx + bv.x, accy + bv.y);
}

// ---------------- Pooling + readout ----------------
__global__ void bounds_kernel(const int* __restrict__ batch, int* __restrict__ gstart) {
    int g = blockIdx.x * blockDim.x + threadIdx.x;
    if (g > N_GRAPHS) return;
    if (g == N_GRAPHS) { gstart[g] = N_NODES; return; }
    int lo = 0, hi = N_NODES;
    while (lo < hi) { int mid = (lo + hi) >> 1; if (batch[mid] < g) lo = mid + 1; else hi = mid; }
    gstart[g] = lo;
}

__global__ void pool_kernel(const float* __restrict__ x, const int* __restrict__ gstart,
                            float* __restrict__ gpool) {
    int g = blockIdx.x >> 3, c = blockIdx.x & 7;
    int t = threadIdx.x;
    int beg = gstart[g], end = gstart[g + 1];
    float acc = 0.f;
    for (int i = beg + c; i < end; i += 8) acc += x[(size_t)i * D + t];
    atomicAdd(&gpool[g * D + t], acc);
}

__global__ void readout_kernel(const float* __restrict__ gpool,
                               const float* __restrict__ W1, const float* __restrict__ b1,
                               const float* __restrict__ W2, const float* __restrict__ b2,
                               float* __restrict__ out) {
    int g = blockIdx.x;
    int t = threadIdx.x;   // 64 threads
    __shared__ float hid[64];
    float a = b1[t];
    for (int k = 0; k < D; ++k) a += gpool[g * D + k] * W1[k * 64 + t];
    hid[t] = fmaxf(a, 0.f);
    __syncthreads();
    if (t < N_TARGETS) {
        float o = b2[t];
        for (int k = 0; k < 64; ++k) o += hid[k] * W2[k * N_TARGETS + t];
        out[g * N_TARGETS + t] = o;
    }
}

extern "C" void kernel_launch(void* const* d_in, const int* in_sizes, int n_in,
                              void* d_out, int out_size, void* d_ws, size_t ws_size,
                              hipStream_t stream) {
    const float* x    = (const float*)d_in[0];
    const int*   ei   = (const int*)d_in[1];
    const int*   batch= (const int*)d_in[2];
    const float* W    = (const float*)d_in[3];
    const float* a_s  = (const float*)d_in[4];
    const float* a_d  = (const float*)d_in[5];
    const float* bias = (const float*)d_in[6];
    const float* W1   = (const float*)d_in[7];
    const float* b1   = (const float*)d_in[8];
    const float* W2   = (const float*)d_in[9];
    const float* b2   = (const float*)d_in[10];
    float* out = (float*)d_out;
    const int* srcp = ei;
    const int* dstp = ei + N_EDGES;

    char* p = (char*)d_ws;
    float* bufA = (float*)p; p += (size_t)N_NODES * D * 4;      // 51.2 MB
    float* bufB = (float*)p; p += (size_t)N_NODES * D * 4;      // 51.2 MB (tmp aliases)
    u16* hb     = (u16*)p;   p += (size_t)N_NODES * D * 2;      // 25.6 MB
    int* csr    = (int*)p;   p += (size_t)E_TOT * 4;            // 6.8 MB
    int* offg   = (int*)p;   p += (size_t)(N_NODES + 1) * 4;
    float* als  = (float*)p; p += (size_t)N_NODES * 4;
    float* ald  = (float*)p; p += (size_t)N_NODES * 4;
    int* cntg   = (int*)p;   p += 256 * NBK * 4;                // 256 KB
    int* bucket_base = (int*)p; p += (NBK + 1) * 4;
    int* gstart = (int*)p;   p += 132 * 4;
    float* gpool = (float*)p; p += N_GRAPHS * D * 4;
    uint2* tmp = (uint2*)bufB;   // 13.6 MB, dead until layer-1 edge output

    hipMemsetAsync(gpool, 0, N_GRAPHS * D * 4, stream);

    histA_kernel<<<256, 256, 0, stream>>>(dstp, cntg);
    scanA_kernel<<<1, 256, 0, stream>>>(cntg, bucket_base);
    scatA_kernel<<<256, 256, 0, stream>>>(srcp, dstp, cntg, tmp);
    bucketB_kernel<<<NBK, 256, 0, stream>>>(tmp, bucket_base, offg, csr);
    bounds_kernel<<<1, 256, 0, stream>>>(batch, gstart);

    const float* cur = x;
    float* outs[3] = {bufA, bufB, bufA};
    for (int l = 0; l < N_LAYERS; ++l) {
        gemm_kernel<<<(N_NODES + 127) / 128, 256, 0, stream>>>(
            cur, W + (size_t)l * D * D, a_s + (size_t)l * D, a_d + (size_t)l * D,
            hb, als, ald);
        edge_kernel<<<(N_NODES * 64 + 255) / 256, 256, 0, stream>>>(
            hb, als, ald, offg, csr, bias + (size_t)l * D, outs[l]);
        cur = outs[l];
    }
    pool_kernel<<<N_GRAPHS * 8, 128, 0, stream>>>(cur, gstart, gpool);
    readout_kernel<<<N_GRAPHS, 64, 0, stream>>>(gpool, W1, b1, W2, b2, out);
}

// Round 15
// 545.464 us; speedup vs baseline: 5.2297x; 1.0318x over previous
//
#include <hip/hip_runtime.h>
#include <math.h>

#define N_NODES 100000
#define N_EDGES 1600000
#define D 128
#define N_LAYERS 3
#define N_GRAPHS 128
#define N_TARGETS 10
#define NEG_SLOPE 0.2f
#define E_TOT (N_EDGES + N_NODES)

#define NBK 256          /* dst buckets */
#define BKT_NODES 391    /* ceil(N_NODES/NBK) */
#define CHUNK 6641       /* ceil(E_TOT/256) edges per pass-A block */
#define SEG_CAP 8192     /* LDS row-build capacity per bucket */

typedef unsigned int u32;
typedef unsigned short u16;
typedef __attribute__((ext_vector_type(8))) short bf16x8;
typedef __attribute__((ext_vector_type(4))) float f32x4;

__device__ __forceinline__ float bf2f(u16 b) {
    u32 u = ((u32)b) << 16;
    return __uint_as_float(u);
}
__device__ __forceinline__ u16 f2bf(float f) {  // round-to-nearest-even
    u32 u = __float_as_uint(f);
    u32 r = (u + 0x7fffu + ((u >> 16) & 1u)) >> 16;
    return (u16)r;
}

// ---------------- CSR build A1: per-block bucket histogram ----------------
__global__ __launch_bounds__(256) void histA_kernel(const int* __restrict__ dst,
                                                    int* __restrict__ cntg) {
    __shared__ int c[NBK];
    int blk = blockIdx.x, tid = threadIdx.x;
    c[tid] = 0;
    __syncthreads();
    int base = blk * CHUNK;
    int end = base + CHUNK; if (end > E_TOT) end = E_TOT;
    for (int i = base + tid; i < end; i += 256) {
        int d = (i < N_EDGES) ? dst[i] : (i - N_EDGES);
        atomicAdd(&c[d / BKT_NODES], 1);
    }
    __syncthreads();
    cntg[blk * NBK + tid] = c[tid];
}

// ---------------- CSR build A2: exact offsets (one block, no global atomics) ----
__global__ __launch_bounds__(256) void scanA_kernel(int* __restrict__ cntg,
                                                    int* __restrict__ bucket_base) {
    __shared__ int tot[NBK];
    __shared__ int sc[NBK];
    int b = threadIdx.x;
    int sum = 0;
    for (int blk = 0; blk < 256; ++blk) {
        int v = cntg[blk * NBK + b];
        cntg[blk * NBK + b] = sum;
        sum += v;
    }
    tot[b] = sum;
    sc[b] = sum;
    __syncthreads();
    for (int o = 1; o < NBK; o <<= 1) {
        int x = (b >= o) ? sc[b - o] : 0;
        __syncthreads();
        sc[b] += x;
        __syncthreads();
    }
    int excl = sc[b] - tot[b];
    bucket_base[b] = excl;
    if (b == NBK - 1) bucket_base[NBK] = excl + tot[b];
    for (int blk = 0; blk < 256; ++blk) cntg[blk * NBK + b] += excl;
}

// ---------------- CSR build A3: scatter pairs bucket-grouped ----------------
__global__ __launch_bounds__(256) void scatA_kernel(const int* __restrict__ src,
                                                    const int* __restrict__ dst,
                                                    const int* __restrict__ cntg,
                                                    uint2* __restrict__ tmp) {
    __shared__ int off[NBK];
    __shared__ int c2[NBK];
    int blk = blockIdx.x, tid = threadIdx.x;
    off[tid] = cntg[blk * NBK + tid];
    c2[tid] = 0;
    __syncthreads();
    int base = blk * CHUNK;
    int end = base + CHUNK; if (end > E_TOT) end = E_TOT;
    for (int i = base + tid; i < end; i += 256) {
        int s, d;
        if (i < N_EDGES) { s = src[i]; d = dst[i]; } else { s = d = i - N_EDGES; }
        int b = d / BKT_NODES;
        int r = atomicAdd(&c2[b], 1);
        tmp[off[b] + r] = make_uint2((u32)s, (u32)d);
    }
}

// ---------------- CSR build B: per-bucket node sort, coalesced CSR write --------
__global__ __launch_bounds__(256) void bucketB_kernel(const uint2* __restrict__ tmp,
                                                      const int* __restrict__ bucket_base,
                                                      int* __restrict__ offg,
                                                      int* __restrict__ csr) {
    __shared__ int dcnt[BKT_NODES + 1];
    __shared__ int lro[BKT_NODES + 1];
    __shared__ int psum[256];
    __shared__ int srow[SEG_CAP];
    int b = blockIdx.x, tid = threadIdx.x;
    int dbase = b * BKT_NODES;
    int nb = N_NODES - dbase; if (nb > BKT_NODES) nb = BKT_NODES;
    int beg = bucket_base[b], end = bucket_base[b + 1];
    int len = end - beg;

    for (int i = tid; i < BKT_NODES + 1; i += 256) dcnt[i] = 0;
    __syncthreads();
    for (int i = tid; i < len; i += 256) {
        uint2 e = tmp[beg + i];
        atomicAdd(&dcnt[(int)e.y - dbase], 1);
    }
    __syncthreads();
    int a0 = (2 * tid     < nb) ? dcnt[2 * tid]     : 0;
    int a1 = (2 * tid + 1 < nb) ? dcnt[2 * tid + 1] : 0;
    psum[tid] = a0 + a1;
    __syncthreads();
    for (int o = 1; o < 256; o <<= 1) {
        int x = (tid >= o) ? psum[tid - o] : 0;
        __syncthreads();
        psum[tid] += x;
        __syncthreads();
    }
    int excl = psum[tid] - (a0 + a1);
    if (2 * tid     < nb) lro[2 * tid]     = excl;
    if (2 * tid + 1 < nb) lro[2 * tid + 1] = excl + a0;
    __syncthreads();
    for (int i = tid; i < nb; i += 256) offg[dbase + i] = beg + lro[i];
    if (b == 0 && tid == 0) offg[N_NODES] = E_TOT;
    for (int i = tid; i < nb; i += 256) dcnt[i] = 0;
    __syncthreads();
    if (len <= SEG_CAP) {
        for (int i = tid; i < len; i += 256) {
            uint2 e = tmp[beg + i];
            int dl = (int)e.y - dbase;
            int r = atomicAdd(&dcnt[dl], 1);
            srow[lro[dl] + r] = (int)e.x;
        }
        __syncthreads();
        for (int i = tid; i < len; i += 256) csr[beg + i] = srow[i];
    } else {
        for (int i = tid; i < len; i += 256) {
            uint2 e = tmp[beg + i];
            int dl = (int)e.y - dbase;
            int r = atomicAdd(&dcnt[dl], 1);
            csr[beg + lro[dl] + r] = (int)e.x;
        }
    }
}

// ---------------- MFMA GEMM: Hb(bf16) = X @ W, als, ald ----------------
// BF16IN=0: X is f32 (first layer). BF16IN=1: X is packed bf16 (layer outputs).
template<int BF16IN>
__global__ __launch_bounds__(256) void gemm_kernel(
        const void* __restrict__ Xv, const float* __restrict__ Wl,
        const float* __restrict__ asr, const float* __restrict__ ads,
        u16* __restrict__ Hb, float* __restrict__ als, float* __restrict__ ald) {
    __shared__ u16 xa[128][136];
    __shared__ u16 wt[128][136];
    int tid = threadIdx.x;
    int row0 = blockIdx.x * 128;

    if (BF16IN) {
        const u16* Xb = (const u16*)Xv;
        #pragma unroll
        for (int i = 0; i < 16; ++i) {
            int e = (i * 256 + tid) * 4;
            int r = e >> 7, c = e & 127;
            int row = row0 + r;
            uint2 v = make_uint2(0u, 0u);
            if (row < N_NODES) v = *(const uint2*)&Xb[(size_t)row * D + c];
            *(uint2*)&xa[r][c] = v;
        }
    } else {
        const float* X = (const float*)Xv;
        #pragma unroll
        for (int i = 0; i < 16; ++i) {
            int e = (i * 256 + tid) * 4;
            int r = e >> 7, c = e & 127;
            int row = row0 + r;
            float4 v = make_float4(0.f, 0.f, 0.f, 0.f);
            if (row < N_NODES) v = *(const float4*)&X[(size_t)row * D + c];
            u32 lo = (u32)f2bf(v.x) | ((u32)f2bf(v.y) << 16);
            u32 hi = (u32)f2bf(v.z) | ((u32)f2bf(v.w) << 16);
            *(uint2*)&xa[r][c] = make_uint2(lo, hi);
        }
    }
    #pragma unroll
    for (int i = 0; i < 16; ++i) {
        int e = (i * 256 + tid) * 4;
        int k = e >> 7, c = e & 127;
        float4 v = *(const float4*)&Wl[e];
        wt[c + 0][k] = f2bf(v.x);
        wt[c + 1][k] = f2bf(v.y);
        wt[c + 2][k] = f2bf(v.z);
        wt[c + 3][k] = f2bf(v.w);
    }
    __syncthreads();

    int wv   = tid >> 6;
    int lane = tid & 63;
    int r16  = lane & 15;
    int g    = lane >> 4;
    int rbase = wv * 32;

    f32x4 acc[2][8];
    #pragma unroll
    for (int rt = 0; rt < 2; ++rt)
        #pragma unroll
        for (int ct = 0; ct < 8; ++ct) acc[rt][ct] = (f32x4){0.f, 0.f, 0.f, 0.f};

    #pragma unroll
    for (int kk = 0; kk < 4; ++kk) {
        int k0 = kk * 32 + g * 8;
        bf16x8 bx0 = *(const bf16x8*)&xa[rbase + r16][k0];
        bf16x8 bx1 = *(const bf16x8*)&xa[rbase + 16 + r16][k0];
        #pragma unroll
        for (int ct = 0; ct < 8; ++ct) {
            bf16x8 aw = *(const bf16x8*)&wt[ct * 16 + r16][k0];
            acc[0][ct] = __builtin_amdgcn_mfma_f32_16x16x32_bf16(aw, bx0, acc[0][ct], 0, 0, 0);
            acc[1][ct] = __builtin_amdgcn_mfma_f32_16x16x32_bf16(aw, bx1, acc[1][ct], 0, 0, 0);
        }
    }

    #pragma unroll
    for (int rt = 0; rt < 2; ++rt) {
        int row = row0 + rbase + rt * 16 + r16;
        float ps = 0.f, pd = 0.f;
        #pragma unroll
        for (int ct = 0; ct < 8; ++ct) {
            float4 av = *(const float4*)&asr[ct * 16 + g * 4];
            float4 dv = *(const float4*)&ads[ct * 16 + g * 4];
            f32x4 a = acc[rt][ct];
            ps += a[0] * av.x + a[1] * av.y + a[2] * av.z + a[3] * av.w;
            pd += a[0] * dv.x + a[1] * dv.y + a[2] * dv.z + a[3] * dv.w;
        }
        ps += __shfl_xor(ps, 16); ps += __shfl_xor(ps, 32);
        pd += __shfl_xor(pd, 16); pd += __shfl_xor(pd, 32);
        if (row < N_NODES) {
            #pragma unroll
            for (int ct = 0; ct < 8; ++ct) {
                f32x4 a = acc[rt][ct];
                u32 lo = (u32)f2bf(a[0]) | ((u32)f2bf(a[1]) << 16);
                u32 hi = (u32)f2bf(a[2]) | ((u32)f2bf(a[3]) << 16);
                *(uint2*)&Hb[(size_t)row * D + ct * 16 + g * 4] = make_uint2(lo, hi);
            }
            if (g == 0) { als[row] = ps; ald[row] = pd; }
        }
    }
}

// ---------------- Edge softmax + aggregate: one wave per dst node ----------------
// Output written as packed bf16 (consumed by next GEMM's bf16 staging / pool).
__global__ __launch_bounds__(256) void edge_kernel(
        const u16* __restrict__ hb, const float* __restrict__ als,
        const float* __restrict__ ald, const int* __restrict__ off,
        const int* __restrict__ csr, const float* __restrict__ bias,
        u16* __restrict__ out) {
    int gtid = blockIdx.x * blockDim.x + threadIdx.x;
    int node = gtid >> 6;
    int lane = threadIdx.x & 63;
    if (node >= N_NODES) return;
    int beg = off[node], end = off[node + 1];
    int deg = end - beg;
    float ad = ald[node];
    float ax0 = 0.f, ay0 = 0.f, ax1 = 0.f, ay1 = 0.f;  // 2 chains: 2x FMA ILP
    const u16* hl = hb + lane * 2;

    if (deg <= 64) {
        int sreg = 0;
        float v = -3.0e38f;
        if (lane < deg) {
            sreg = csr[beg + lane];
            float t = als[sreg] + ad;
            v = (t > 0.f) ? t : NEG_SLOPE * t;
        }
        float m = v;
        #pragma unroll
        for (int o = 1; o < 64; o <<= 1) m = fmaxf(m, __shfl_xor(m, o));
        float w = (lane < deg) ? __expf(v - m) : 0.f;
        float sum = w;
        #pragma unroll
        for (int o = 1; o < 64; o <<= 1) sum += __shfl_xor(sum, o);
        w *= 1.f / sum;

        int e = 0;
        for (; e + 8 <= deg; e += 8) {
            u32 o32[8]; float wv[8]; ushort2 hv[8];
            #pragma unroll
            for (int k = 0; k < 8; ++k) {
                o32[k] = (u32)__shfl(sreg, e + k) * D;   // 32-bit addr math
                wv[k] = __shfl(w, e + k);
            }
            #pragma unroll
            for (int k = 0; k < 8; ++k) hv[k] = *(const ushort2*)(hl + o32[k]);
            #pragma unroll
            for (int k = 0; k < 4; ++k) {
                ax0 += wv[k] * bf2f(hv[k].x);
                ay0 += wv[k] * bf2f(hv[k].y);
            }
            #pragma unroll
            for (int k = 4; k < 8; ++k) {
                ax1 += wv[k] * bf2f(hv[k].x);
                ay1 += wv[k] * bf2f(hv[k].y);
            }
        }
        for (; e < deg; ++e) {
            u32 o0 = (u32)__shfl(sreg, e) * D;
            float w0 = __shfl(w, e);
            ushort2 h0 = *(const ushort2*)(hl + o0);
            ax0 += w0 * bf2f(h0.x);
            ay0 += w0 * bf2f(h0.y);
        }
    } else {
        // generic path over the contiguous CSR segment (any degree)
        float lm = -3.0e38f;
        for (int j = lane; j < deg; j += 64) {
            int s = csr[beg + j];
            float t = als[s] + ad;
            t = (t > 0.f) ? t : NEG_SLOPE * t;
            lm = fmaxf(lm, t);
        }
        #pragma unroll
        for (int o = 1; o < 64; o <<= 1) lm = fmaxf(lm, __shfl_xor(lm, o));
        float m = lm;
        float lsum = 0.f;
        for (int j = lane; j < deg; j += 64) {
            int s = csr[beg + j];
            float t = als[s] + ad;
            t = (t > 0.f) ? t : NEG_SLOPE * t;
            lsum += __expf(t - m);
        }
        #pragma unroll
        for (int o = 1; o < 64; o <<= 1) lsum += __shfl_xor(lsum, o);
        float invden = 1.f / lsum;
        for (int e = 0; e < deg; ++e) {
            int s = csr[beg + e];
            float t = als[s] + ad;
            t = (t > 0.f) ? t : NEG_SLOPE * t;
            float w = __expf(t - m) * invden;
            ushort2 hv = *(const ushort2*)(hl + (u32)s * D);
            ax0 += w * bf2f(hv.x);
            ay0 += w * bf2f(hv.y);
        }
    }

    float2 bv = *(const float2*)(bias + lane * 2);
    float rx = ax0 + ax1 + bv.x;
    float ry = ay0 + ay1 + bv.y;
    u32 pk = (u32)f2bf(rx) | ((u32)f2bf(ry) << 16);
    *(u32*)&out[(size_t)node * D + lane * 2] = pk;
}

// ---------------- Pooling + readout ----------------
__global__ void bounds_kernel(const int* __restrict__ batch, int* __restrict__ gstart) {
    int g = blockIdx.x * blockDim.x + threadIdx.x;
    if (g > N_GRAPHS) return;
    if (g == N_GRAPHS) { gstart[g] = N_NODES; return; }
    int lo = 0, hi = N_NODES;
    while (lo < hi) { int mid = (lo + hi) >> 1; if (batch[mid] < g) lo = mid + 1; else hi = mid; }
    gstart[g] = lo;
}

__global__ void pool_kernel(const u16* __restrict__ x, const int* __restrict__ gstart,
                            float* __restrict__ gpool) {
    int g = blockIdx.x >> 3, c = blockIdx.x & 7;
    int t = threadIdx.x;
    int beg = gstart[g], end = gstart[g + 1];
    float acc = 0.f;
    for (int i = beg + c; i < end; i += 8) acc += bf2f(x[(size_t)i * D + t]);
    atomicAdd(&gpool[g * D + t], acc);
}

__global__ void readout_kernel(const float* __restrict__ gpool,
                               const float* __restrict__ W1, const float* __restrict__ b1,
                               const float* __restrict__ W2, const float* __restrict__ b2,
                               float* __restrict__ out) {
    int g = blockIdx.x;
    int t = threadIdx.x;   // 64 threads
    __shared__ float hid[64];
    float a = b1[t];
    for (int k = 0; k < D; ++k) a += gpool[g * D + k] * W1[k * 64 + t];
    hid[t] = fmaxf(a, 0.f);
    __syncthreads();
    if (t < N_TARGETS) {
        float o = b2[t];
        for (int k = 0; k < 64; ++k) o += hid[k] * W2[k * N_TARGETS + t];
        out[g * N_TARGETS + t] = o;
    }
}

extern "C" void kernel_launch(void* const* d_in, const int* in_sizes, int n_in,
                              void* d_out, int out_size, void* d_ws, size_t ws_size,
                              hipStream_t stream) {
    const float* x    = (const float*)d_in[0];
    const int*   ei   = (const int*)d_in[1];
    const int*   batch= (const int*)d_in[2];
    const float* W    = (const float*)d_in[3];
    const float* a_s  = (const float*)d_in[4];
    const float* a_d  = (const float*)d_in[5];
    const float* bias = (const float*)d_in[6];
    const float* W1   = (const float*)d_in[7];
    const float* b1   = (const float*)d_in[8];
    const float* W2   = (const float*)d_in[9];
    const float* b2   = (const float*)d_in[10];
    float* out = (float*)d_out;
    const int* srcp = ei;
    const int* dstp = ei + N_EDGES;

    char* p = (char*)d_ws;
    u16* bufA   = (u16*)p;   p += (size_t)N_NODES * D * 4;      // bf16 out bufs (regions kept
    u16* bufB   = (u16*)p;   p += (size_t)N_NODES * D * 4;      //  f32-sized; tmp aliases B)
    u16* hb     = (u16*)p;   p += (size_t)N_NODES * D * 2;
    int* csr    = (int*)p;   p += (size_t)E_TOT * 4;
    int* offg   = (int*)p;   p += (size_t)(N_NODES + 1) * 4;
    float* als  = (float*)p; p += (size_t)N_NODES * 4;
    float* ald  = (float*)p; p += (size_t)N_NODES * 4;
    int* cntg   = (int*)p;   p += 256 * NBK * 4;
    int* bucket_base = (int*)p; p += (NBK + 1) * 4;
    int* gstart = (int*)p;   p += 132 * 4;
    float* gpool = (float*)p; p += N_GRAPHS * D * 4;
    uint2* tmp = (uint2*)bufB;   // 13.6 MB, dead until layer-1 edge output

    hipMemsetAsync(gpool, 0, N_GRAPHS * D * 4, stream);

    histA_kernel<<<256, 256, 0, stream>>>(dstp, cntg);
    scanA_kernel<<<1, 256, 0, stream>>>(cntg, bucket_base);
    scatA_kernel<<<256, 256, 0, stream>>>(srcp, dstp, cntg, tmp);
    bucketB_kernel<<<NBK, 256, 0, stream>>>(tmp, bucket_base, offg, csr);
    bounds_kernel<<<1, 256, 0, stream>>>(batch, gstart);

    int gb = (N_NODES + 127) / 128;
    int ebk = (N_NODES * 64 + 255) / 256;
    u16* outs[3] = {bufA, bufB, bufA};

    // layer 0: f32 input
    gemm_kernel<0><<<gb, 256, 0, stream>>>(x, W, a_s, a_d, hb, als, ald);
    edge_kernel<<<ebk, 256, 0, stream>>>(hb, als, ald, offg, csr, bias, outs[0]);
    // layers 1..2: bf16 input
    for (int l = 1; l < N_LAYERS; ++l) {
        gemm_kernel<1><<<gb, 256, 0, stream>>>(
            outs[l - 1], W + (size_t)l * D * D, a_s + (size_t)l * D, a_d + (size_t)l * D,
            hb, als, ald);
        edge_kernel<<<ebk, 256, 0, stream>>>(
            hb, als, ald, offg, csr, bias + (size_t)l * D, outs[l]);
    }
    pool_kernel<<<N_GRAPHS * 8, 128, 0, stream>>>(outs[2], gstart, gpool);
    readout_kernel<<<N_GRAPHS, 64, 0, stream>>>(gpool, W1, b1, W2, b2, out);
}

// Round 16
// 545.029 us; speedup vs baseline: 5.2338x; 1.0008x over previous
//
#include <hip/hip_runtime.h>
#include <math.h>

#define N_NODES 100000
#define N_EDGES 1600000
#define D 128
#define N_LAYERS 3
#define N_GRAPHS 128
#define N_TARGETS 10
#define NEG_SLOPE 0.2f
#define E_TOT (N_EDGES + N_NODES)

#define NBK 256          /* dst buckets */
#define BKT_NODES 391    /* ceil(N_NODES/NBK) */
#define CHUNK 6641       /* ceil(E_TOT/256) edges per pass-A block */
#define SEG_CAP 8192     /* LDS row-build capacity per bucket */

typedef unsigned int u32;
typedef unsigned short u16;
typedef __attribute__((ext_vector_type(8))) short bf16x8;
typedef __attribute__((ext_vector_type(4))) float f32x4;

__device__ __forceinline__ float bf2f(u16 b) {
    u32 u = ((u32)b) << 16;
    return __uint_as_float(u);
}
__device__ __forceinline__ u16 f2bf(float f) {  // round-to-nearest-even
    u32 u = __float_as_uint(f);
    u32 r = (u + 0x7fffu + ((u >> 16) & 1u)) >> 16;
    return (u16)r;
}

// ---------------- CSR build A1: per-block bucket histogram ----------------
__global__ __launch_bounds__(256) void histA_kernel(const int* __restrict__ dst,
                                                    int* __restrict__ cntg) {
    __shared__ int c[NBK];
    int blk = blockIdx.x, tid = threadIdx.x;
    c[tid] = 0;
    __syncthreads();
    int base = blk * CHUNK;
    int end = base + CHUNK; if (end > E_TOT) end = E_TOT;
    for (int i = base + tid; i < end; i += 256) {
        int d = (i < N_EDGES) ? dst[i] : (i - N_EDGES);
        atomicAdd(&c[d / BKT_NODES], 1);
    }
    __syncthreads();
    cntg[blk * NBK + tid] = c[tid];
}

// ---------------- CSR build A2: exact offsets (one block, no global atomics) ----
__global__ __launch_bounds__(256) void scanA_kernel(int* __restrict__ cntg,
                                                    int* __restrict__ bucket_base) {
    __shared__ int tot[NBK];
    __shared__ int sc[NBK];
    int b = threadIdx.x;
    int sum = 0;
    for (int blk = 0; blk < 256; ++blk) {
        int v = cntg[blk * NBK + b];
        cntg[blk * NBK + b] = sum;
        sum += v;
    }
    tot[b] = sum;
    sc[b] = sum;
    __syncthreads();
    for (int o = 1; o < NBK; o <<= 1) {
        int x = (b >= o) ? sc[b - o] : 0;
        __syncthreads();
        sc[b] += x;
        __syncthreads();
    }
    int excl = sc[b] - tot[b];
    bucket_base[b] = excl;
    if (b == NBK - 1) bucket_base[NBK] = excl + tot[b];
    for (int blk = 0; blk < 256; ++blk) cntg[blk * NBK + b] += excl;
}

// ---------------- CSR build A3: scatter pairs bucket-grouped ----------------
__global__ __launch_bounds__(256) void scatA_kernel(const int* __restrict__ src,
                                                    const int* __restrict__ dst,
                                                    const int* __restrict__ cntg,
                                                    uint2* __restrict__ tmp) {
    __shared__ int off[NBK];
    __shared__ int c2[NBK];
    int blk = blockIdx.x, tid = threadIdx.x;
    off[tid] = cntg[blk * NBK + tid];
    c2[tid] = 0;
    __syncthreads();
    int base = blk * CHUNK;
    int end = base + CHUNK; if (end > E_TOT) end = E_TOT;
    for (int i = base + tid; i < end; i += 256) {
        int s, d;
        if (i < N_EDGES) { s = src[i]; d = dst[i]; } else { s = d = i - N_EDGES; }
        int b = d / BKT_NODES;
        int r = atomicAdd(&c2[b], 1);
        tmp[off[b] + r] = make_uint2((u32)s, (u32)d);
    }
}

// ---------------- CSR build B: per-bucket node sort, coalesced CSR write --------
__global__ __launch_bounds__(256) void bucketB_kernel(const uint2* __restrict__ tmp,
                                                      const int* __restrict__ bucket_base,
                                                      int* __restrict__ offg,
                                                      int* __restrict__ csr) {
    __shared__ int dcnt[BKT_NODES + 1];
    __shared__ int lro[BKT_NODES + 1];
    __shared__ int psum[256];
    __shared__ int srow[SEG_CAP];
    int b = blockIdx.x, tid = threadIdx.x;
    int dbase = b * BKT_NODES;
    int nb = N_NODES - dbase; if (nb > BKT_NODES) nb = BKT_NODES;
    int beg = bucket_base[b], end = bucket_base[b + 1];
    int len = end - beg;

    for (int i = tid; i < BKT_NODES + 1; i += 256) dcnt[i] = 0;
    __syncthreads();
    for (int i = tid; i < len; i += 256) {
        uint2 e = tmp[beg + i];
        atomicAdd(&dcnt[(int)e.y - dbase], 1);
    }
    __syncthreads();
    int a0 = (2 * tid     < nb) ? dcnt[2 * tid]     : 0;
    int a1 = (2 * tid + 1 < nb) ? dcnt[2 * tid + 1] : 0;
    psum[tid] = a0 + a1;
    __syncthreads();
    for (int o = 1; o < 256; o <<= 1) {
        int x = (tid >= o) ? psum[tid - o] : 0;
        __syncthreads();
        psum[tid] += x;
        __syncthreads();
    }
    int excl = psum[tid] - (a0 + a1);
    if (2 * tid     < nb) lro[2 * tid]     = excl;
    if (2 * tid + 1 < nb) lro[2 * tid + 1] = excl + a0;
    __syncthreads();
    for (int i = tid; i < nb; i += 256) offg[dbase + i] = beg + lro[i];
    if (b == 0 && tid == 0) offg[N_NODES] = E_TOT;
    for (int i = tid; i < nb; i += 256) dcnt[i] = 0;
    __syncthreads();
    if (len <= SEG_CAP) {
        for (int i = tid; i < len; i += 256) {
            uint2 e = tmp[beg + i];
            int dl = (int)e.y - dbase;
            int r = atomicAdd(&dcnt[dl], 1);
            srow[lro[dl] + r] = (int)e.x;
        }
        __syncthreads();
        for (int i = tid; i < len; i += 256) csr[beg + i] = srow[i];
    } else {
        for (int i = tid; i < len; i += 256) {
            uint2 e = tmp[beg + i];
            int dl = (int)e.y - dbase;
            int r = atomicAdd(&dcnt[dl], 1);
            csr[beg + lro[dl] + r] = (int)e.x;
        }
    }
}

// ---------------- MFMA GEMM: Hb(bf16) = X @ W, als, ald ----------------
template<int BF16IN>
__global__ __launch_bounds__(256) void gemm_kernel(
        const void* __restrict__ Xv, const float* __restrict__ Wl,
        const float* __restrict__ asr, const float* __restrict__ ads,
        u16* __restrict__ Hb, float* __restrict__ als, float* __restrict__ ald) {
    __shared__ u16 xa[128][136];
    __shared__ u16 wt[128][136];
    int tid = threadIdx.x;
    int row0 = blockIdx.x * 128;

    if (BF16IN) {
        const u16* Xb = (const u16*)Xv;
        #pragma unroll
        for (int i = 0; i < 16; ++i) {
            int e = (i * 256 + tid) * 4;
            int r = e >> 7, c = e & 127;
            int row = row0 + r;
            uint2 v = make_uint2(0u, 0u);
            if (row < N_NODES) v = *(const uint2*)&Xb[(size_t)row * D + c];
            *(uint2*)&xa[r][c] = v;
        }
    } else {
        const float* X = (const float*)Xv;
        #pragma unroll
        for (int i = 0; i < 16; ++i) {
            int e = (i * 256 + tid) * 4;
            int r = e >> 7, c = e & 127;
            int row = row0 + r;
            float4 v = make_float4(0.f, 0.f, 0.f, 0.f);
            if (row < N_NODES) v = *(const float4*)&X[(size_t)row * D + c];
            u32 lo = (u32)f2bf(v.x) | ((u32)f2bf(v.y) << 16);
            u32 hi = (u32)f2bf(v.z) | ((u32)f2bf(v.w) << 16);
            *(uint2*)&xa[r][c] = make_uint2(lo, hi);
        }
    }
    #pragma unroll
    for (int i = 0; i < 16; ++i) {
        int e = (i * 256 + tid) * 4;
        int k = e >> 7, c = e & 127;
        float4 v = *(const float4*)&Wl[e];
        wt[c + 0][k] = f2bf(v.x);
        wt[c + 1][k] = f2bf(v.y);
        wt[c + 2][k] = f2bf(v.z);
        wt[c + 3][k] = f2bf(v.w);
    }
    __syncthreads();

    int wv   = tid >> 6;
    int lane = tid & 63;
    int r16  = lane & 15;
    int g    = lane >> 4;
    int rbase = wv * 32;

    f32x4 acc[2][8];
    #pragma unroll
    for (int rt = 0; rt < 2; ++rt)
        #pragma unroll
        for (int ct = 0; ct < 8; ++ct) acc[rt][ct] = (f32x4){0.f, 0.f, 0.f, 0.f};

    #pragma unroll
    for (int kk = 0; kk < 4; ++kk) {
        int k0 = kk * 32 + g * 8;
        bf16x8 bx0 = *(const bf16x8*)&xa[rbase + r16][k0];
        bf16x8 bx1 = *(const bf16x8*)&xa[rbase + 16 + r16][k0];
        #pragma unroll
        for (int ct = 0; ct < 8; ++ct) {
            bf16x8 aw = *(const bf16x8*)&wt[ct * 16 + r16][k0];
            acc[0][ct] = __builtin_amdgcn_mfma_f32_16x16x32_bf16(aw, bx0, acc[0][ct], 0, 0, 0);
            acc[1][ct] = __builtin_amdgcn_mfma_f32_16x16x32_bf16(aw, bx1, acc[1][ct], 0, 0, 0);
        }
    }

    #pragma unroll
    for (int rt = 0; rt < 2; ++rt) {
        int row = row0 + rbase + rt * 16 + r16;
        float ps = 0.f, pd = 0.f;
        #pragma unroll
        for (int ct = 0; ct < 8; ++ct) {
            float4 av = *(const float4*)&asr[ct * 16 + g * 4];
            float4 dv = *(const float4*)&ads[ct * 16 + g * 4];
            f32x4 a = acc[rt][ct];
            ps += a[0] * av.x + a[1] * av.y + a[2] * av.z + a[3] * av.w;
            pd += a[0] * dv.x + a[1] * dv.y + a[2] * dv.z + a[3] * dv.w;
        }
        ps += __shfl_xor(ps, 16); ps += __shfl_xor(ps, 32);
        pd += __shfl_xor(pd, 16); pd += __shfl_xor(pd, 32);
        if (row < N_NODES) {
            #pragma unroll
            for (int ct = 0; ct < 8; ++ct) {
                f32x4 a = acc[rt][ct];
                u32 lo = (u32)f2bf(a[0]) | ((u32)f2bf(a[1]) << 16);
                u32 hi = (u32)f2bf(a[2]) | ((u32)f2bf(a[3]) << 16);
                *(uint2*)&Hb[(size_t)row * D + ct * 16 + g * 4] = make_uint2(lo, hi);
            }
            if (g == 0) { als[row] = ps; ald[row] = pd; }
        }
    }
}

// ---------------- Edge softmax + aggregate: one wave per dst node ----------------
// Aggregation: lane owns 4 dims (l32*4); lanes 0-31 serve edge e, lanes 32-63
// edge e+1 -> one dwordx2 load covers TWO full 256B rows; one bpermute per pair
// broadcasts (s,w). Final shfl_xor(32) cross-half reduce; half-wave bf16 store.
__global__ __launch_bounds__(256) void edge_kernel(
        const u16* __restrict__ hb, const float* __restrict__ als,
        const float* __restrict__ ald, const int* __restrict__ off,
        const int* __restrict__ csr, const float* __restrict__ bias,
        u16* __restrict__ out) {
    int gtid = blockIdx.x * blockDim.x + threadIdx.x;
    int node = gtid >> 6;
    int lane = threadIdx.x & 63;
    if (node >= N_NODES) return;
    int beg = off[node], end = off[node + 1];
    int deg = end - beg;
    float ad = ald[node];
    int half = lane >> 5;        // 0: edge e, 1: edge e+1
    int l32 = lane & 31;
    const u16* hq = hb + l32 * 4;   // 4 dims/lane
    float4 acc = make_float4(0.f, 0.f, 0.f, 0.f);
    float4 acc2 = make_float4(0.f, 0.f, 0.f, 0.f);

    if (deg <= 64) {
        int sreg = 0;
        float v = -3.0e38f;
        if (lane < deg) {
            sreg = csr[beg + lane];
            float t = als[sreg] + ad;
            v = (t > 0.f) ? t : NEG_SLOPE * t;
        }
        float m = v;
        #pragma unroll
        for (int o = 1; o < 64; o <<= 1) m = fmaxf(m, __shfl_xor(m, o));
        float w = (lane < deg) ? __expf(v - m) : 0.f;
        float sum = w;
        #pragma unroll
        for (int o = 1; o < 64; o <<= 1) sum += __shfl_xor(sum, o);
        w *= 1.f / sum;

        int e = 0;
        for (; e + 8 <= deg; e += 8) {           // 8 edges = 4 independent loads
            u32 o0 = (u32)__shfl(sreg, e     + half) * D;
            u32 o1 = (u32)__shfl(sreg, e + 2 + half) * D;
            u32 o2 = (u32)__shfl(sreg, e + 4 + half) * D;
            u32 o3 = (u32)__shfl(sreg, e + 6 + half) * D;
            float w0 = __shfl(w, e     + half);
            float w1 = __shfl(w, e + 2 + half);
            float w2 = __shfl(w, e + 4 + half);
            float w3 = __shfl(w, e + 6 + half);
            ushort4 h0 = *(const ushort4*)(hq + o0);
            ushort4 h1 = *(const ushort4*)(hq + o1);
            ushort4 h2 = *(const ushort4*)(hq + o2);
            ushort4 h3 = *(const ushort4*)(hq + o3);
            acc.x += w0 * bf2f(h0.x); acc.y += w0 * bf2f(h0.y);
            acc.z += w0 * bf2f(h0.z); acc.w += w0 * bf2f(h0.w);
            acc2.x += w1 * bf2f(h1.x); acc2.y += w1 * bf2f(h1.y);
            acc2.z += w1 * bf2f(h1.z); acc2.w += w1 * bf2f(h1.w);
            acc.x += w2 * bf2f(h2.x); acc.y += w2 * bf2f(h2.y);
            acc.z += w2 * bf2f(h2.z); acc.w += w2 * bf2f(h2.w);
            acc2.x += w3 * bf2f(h3.x); acc2.y += w3 * bf2f(h3.y);
            acc2.z += w3 * bf2f(h3.z); acc2.w += w3 * bf2f(h3.w);
        }
        for (; e + 2 <= deg; e += 2) {           // pair tail
            u32 o0 = (u32)__shfl(sreg, e + half) * D;
            float w0 = __shfl(w, e + half);
            ushort4 h0 = *(const ushort4*)(hq + o0);
            acc.x += w0 * bf2f(h0.x); acc.y += w0 * bf2f(h0.y);
            acc.z += w0 * bf2f(h0.z); acc.w += w0 * bf2f(h0.w);
        }
        if (e < deg) {                            // single tail: upper half idle
            u32 o0 = (u32)__shfl(sreg, e) * D;
            float w0 = half ? 0.f : __shfl(w, e);
            ushort4 h0 = *(const ushort4*)(hq + o0);
            acc.x += w0 * bf2f(h0.x); acc.y += w0 * bf2f(h0.y);
            acc.z += w0 * bf2f(h0.z); acc.w += w0 * bf2f(h0.w);
        }
    } else {
        // generic path (deg > 64): 3 passes over contiguous CSR segment
        float lm = -3.0e38f;
        for (int j = lane; j < deg; j += 64) {
            int s = csr[beg + j];
            float t = als[s] + ad;
            t = (t > 0.f) ? t : NEG_SLOPE * t;
            lm = fmaxf(lm, t);
        }
        #pragma unroll
        for (int o = 1; o < 64; o <<= 1) lm = fmaxf(lm, __shfl_xor(lm, o));
        float m = lm;
        float lsum = 0.f;
        for (int j = lane; j < deg; j += 64) {
            int s = csr[beg + j];
            float t = als[s] + ad;
            t = (t > 0.f) ? t : NEG_SLOPE * t;
            lsum += __expf(t - m);
        }
        #pragma unroll
        for (int o = 1; o < 64; o <<= 1) lsum += __shfl_xor(lsum, o);
        float invden = 1.f / lsum;
        int e = 0;
        for (; e + 2 <= deg; e += 2) {
            int s = csr[beg + e + half];          // 2 addrs per wave
            float t = als[s] + ad;
            t = (t > 0.f) ? t : NEG_SLOPE * t;
            float w0 = __expf(t - m) * invden;
            ushort4 h0 = *(const ushort4*)(hq + (u32)s * D);
            acc.x += w0 * bf2f(h0.x); acc.y += w0 * bf2f(h0.y);
            acc.z += w0 * bf2f(h0.z); acc.w += w0 * bf2f(h0.w);
        }
        if (e < deg) {
            int s = csr[beg + e];
            float t = als[s] + ad;
            t = (t > 0.f) ? t : NEG_SLOPE * t;
            float w0 = half ? 0.f : __expf(t - m) * invden;
            ushort4 h0 = *(const ushort4*)(hq + (u32)s * D);
            acc.x += w0 * bf2f(h0.x); acc.y += w0 * bf2f(h0.y);
            acc.z += w0 * bf2f(h0.z); acc.w += w0 * bf2f(h0.w);
        }
    }

    acc.x += acc2.x; acc.y += acc2.y; acc.z += acc2.z; acc.w += acc2.w;
    acc.x += __shfl_xor(acc.x, 32);
    acc.y += __shfl_xor(acc.y, 32);
    acc.z += __shfl_xor(acc.z, 32);
    acc.w += __shfl_xor(acc.w, 32);
    if (half == 0) {
        float4 bv = *(const float4*)(bias + l32 * 4);
        u32 lo = (u32)f2bf(acc.x + bv.x) | ((u32)f2bf(acc.y + bv.y) << 16);
        u32 hi = (u32)f2bf(acc.z + bv.z) | ((u32)f2bf(acc.w + bv.w) << 16);
        *(uint2*)&out[(size_t)node * D + l32 * 4] = make_uint2(lo, hi);
    }
}

// ---------------- Pooling + readout ----------------
__global__ void bounds_kernel(const int* __restrict__ batch, int* __restrict__ gstart) {
    int g = blockIdx.x * blockDim.x + threadIdx.x;
    if (g > N_GRAPHS) return;
    if (g == N_GRAPHS) { gstart[g] = N_NODES; return; }
    int lo = 0, hi = N_NODES;
    while (lo < hi) { int mid = (lo + hi) >> 1; if (batch[mid] < g) lo = mid + 1; else hi = mid; }
    gstart[g] = lo;
}

__global__ void pool_kernel(const u16* __restrict__ x, const int* __restrict__ gstart,
                            float* __restrict__ gpool) {
    int g = blockIdx.x >> 3, c = blockIdx.x & 7;
    int t = threadIdx.x;
    int beg = gstart[g], end = gstart[g + 1];
    float acc = 0.f;
    for (int i = beg + c; i < end; i += 8) acc += bf2f(x[(size_t)i * D + t]);
    atomicAdd(&gpool[g * D + t], acc);
}

__global__ void readout_kernel(const float* __restrict__ gpool,
                               const float* __restrict__ W1, const float* __restrict__ b1,
                               const float* __restrict__ W2, const float* __restrict__ b2,
                               float* __restrict__ out) {
    int g = blockIdx.x;
    int t = threadIdx.x;   // 64 threads
    __shared__ float hid[64];
    float a = b1[t];
    for (int k = 0; k < D; ++k) a += gpool[g * D + k] * W1[k * 64 + t];
    hid[t] = fmaxf(a, 0.f);
    __syncthreads();
    if (t < N_TARGETS) {
        float o = b2[t];
        for (int k = 0; k < 64; ++k) o += hid[k] * W2[k * N_TARGETS + t];
        out[g * N_TARGETS + t] = o;
    }
}

extern "C" void kernel_launch(void* const* d_in, const int* in_sizes, int n_in,
                              void* d_out, int out_size, void* d_ws, size_t ws_size,
                              hipStream_t stream) {
    const float* x    = (const float*)d_in[0];
    const int*   ei   = (const int*)d_in[1];
    const int*   batch= (const int*)d_in[2];
    const float* W    = (const float*)d_in[3];
    const float* a_s  = (const float*)d_in[4];
    const float* a_d  = (const float*)d_in[5];
    const float* bias = (const float*)d_in[6];
    const float* W1   = (const float*)d_in[7];
    const float* b1   = (const float*)d_in[8];
    const float* W2   = (const float*)d_in[9];
    const float* b2   = (const float*)d_in[10];
    float* out = (float*)d_out;
    const int* srcp = ei;
    const int* dstp = ei + N_EDGES;

    char* p = (char*)d_ws;
    u16* bufA   = (u16*)p;   p += (size_t)N_NODES * D * 4;
    u16* bufB   = (u16*)p;   p += (size_t)N_NODES * D * 4;
    u16* hb     = (u16*)p;   p += (size_t)N_NODES * D * 2;
    int* csr    = (int*)p;   p += (size_t)E_TOT * 4;
    int* offg   = (int*)p;   p += (size_t)(N_NODES + 1) * 4;
    float* als  = (float*)p; p += (size_t)N_NODES * 4;
    float* ald  = (float*)p; p += (size_t)N_NODES * 4;
    int* cntg   = (int*)p;   p += 256 * NBK * 4;
    int* bucket_base = (int*)p; p += (NBK + 1) * 4;
    int* gstart = (int*)p;   p += 132 * 4;
    float* gpool = (float*)p; p += N_GRAPHS * D * 4;
    uint2* tmp = (uint2*)bufB;

    hipMemsetAsync(gpool, 0, N_GRAPHS * D * 4, stream);

    histA_kernel<<<256, 256, 0, stream>>>(dstp, cntg);
    scanA_kernel<<<1, 256, 0, stream>>>(cntg, bucket_base);
    scatA_kernel<<<256, 256, 0, stream>>>(srcp, dstp, cntg, tmp);
    bucketB_kernel<<<NBK, 256, 0, stream>>>(tmp, bucket_base, offg, csr);
    bounds_kernel<<<1, 256, 0, stream>>>(batch, gstart);

    int gb = (N_NODES + 127) / 128;
    int ebk = (N_NODES * 64 + 255) / 256;
    u16* outs[3] = {bufA, bufB, bufA};

    gemm_kernel<0><<<gb, 256, 0, stream>>>(x, W, a_s, a_d, hb, als, ald);
    edge_kernel<<<ebk, 256, 0, stream>>>(hb, als, ald, offg, csr, bias, outs[0]);
    for (int l = 1; l < N_LAYERS; ++l) {
        gemm_kernel<1><<<gb, 256, 0, stream>>>(
            outs[l - 1], W + (size_t)l * D * D, a_s + (size_t)l * D, a_d + (size_t)l * D,
            hb, als, ald);
        edge_kernel<<<ebk, 256, 0, stream>>>(
            hb, als, ald, offg, csr, bias + (size_t)l * D, outs[l]);
    }
    pool_kernel<<<N_GRAPHS * 8, 128, 0, stream>>>(outs[2], gstart, gpool);
    readout_kernel<<<N_GRAPHS, 64, 0, stream>>>(gpool, W1, b1, W2, b2, out);
}